// Round 11
// baseline (133.380 us; speedup 1.0000x reference)
//
#include <hip/hip_runtime.h>
#include <hip/hip_bf16.h>
#include <hip/hip_fp16.h>
#include <math.h>

#define B_  4
#define S_  4096
#define D_  1024
#define M_  (B_ * S_)   // 16384 rows
#define K_  D_          // 1024 reduction
#define L_  32          // scan chunk length
#define NC_ (S_ / L_)   // 128 chunks per sequence
#define NKT 32          // K_/32 K-tiles (BK=32)

typedef __attribute__((ext_vector_type(8)))  short          bf16x8;
typedef __attribute__((ext_vector_type(8)))  unsigned short u16x8;
typedef __attribute__((ext_vector_type(16))) float          f32x16;

__device__ __forceinline__ unsigned short f2bf(float f) {
    union { __hip_bfloat16 h; unsigned short u; } cv;
    cv.h = __float2bfloat16(f);
    return cv.u;
}

__device__ __forceinline__ float fast_rcp(float x) {
#if __has_builtin(__builtin_amdgcn_rcpf)
    return __builtin_amdgcn_rcpf(x);
#else
    return 1.0f / x;
#endif
}

__device__ __forceinline__ void stage16(const unsigned short* src, char* dst) {
    __builtin_amdgcn_global_load_lds(
        (const __attribute__((address_space(1))) unsigned int*)src,
        (__attribute__((address_space(3))) unsigned int*)dst, 16, 0, 0);
}

// ---------------------------------------------------------------------------
// Kernel 0: fp32 -> bf16 pre-convert, x and W in ONE launch
// ---------------------------------------------------------------------------
__global__ __launch_bounds__(256) void to_bf16_both(
    const float* __restrict__ x, const float* __restrict__ W,
    unsigned short* __restrict__ xb, unsigned short* __restrict__ Wb,
    int n8x, int n8w)
{
    int i = blockIdx.x * 256 + threadIdx.x;
    const float* src;
    unsigned short* dst;
    int j;
    if (i < n8x) { src = x; dst = xb; j = i; }
    else {
        j = i - n8x;
        if (j >= n8w) return;
        src = W; dst = Wb;
    }
    const float4* p = (const float4*)src + (size_t)j * 2;
    float4 a = p[0], b = p[1];
    u16x8 o;
    o[0] = f2bf(a.x); o[1] = f2bf(a.y); o[2] = f2bf(a.z); o[3] = f2bf(a.w);
    o[4] = f2bf(b.x); o[5] = f2bf(b.y); o[6] = f2bf(b.z); o[7] = f2bf(b.w);
    *(u16x8*)(dst + (size_t)j * 8) = o;
}

// ---------------------------------------------------------------------------
// Kernel 1: bf16 MFMA GEMM using 32x32x16 MFMA (2495 TF ubench vs 2075 for
// 16x16x32: +20% rate, half the MFMA instrs), 3-deep counted-vmcnt LDS
// pipeline, fused linear-domain pointwise + fused chunk-(C,V) reduction.
//
// Geometry: BM=256, BN=128d x {h,g}, BK=32, 8 waves (2m x 4n), wave tile
// 128m x 32d x {h,g}: 4 mt-tiles x {acch,accg} of 32x32 (8 x f32x16 = 128
// acc regs, 2 waves/SIMD). LDS: 3 bufs x 32KB (A[256][32]bf16 @0,
// B[256][32] @16384: rows 0-127 hidden W, 128-255 gate).
// Swizzle involution slot^=(row>>1)&3 on BOTH stage-source and read
// (0 conflicts rounds 3-10; tile-base rows =0 mod 32 keeps sx=(r31>>1)&3).
// Frag layouts (32x32x16): A/B: row|col = lane&31, k = (lane>>5)*8+i;
// C/D: col = lane&31, row = (reg&3)+8*(reg>>2)+4*(lane>>5)  [m74/m101].
// Schedule/tile: 2 phases (kh=0,1) x {6 frag reads, stage half of t+2,
// bar, lgk0, 8 MFMA w/setprio, bar}; counted vmcnt(4), never 0 till tail.
// Chunk fusion: one chunk = one mt tile; per-lane 4 group-folds (rows
// 8q+4*l5..+3), shfl_xor(32) pair-compose, fold; l5==0 lanes write CVagg
// (32 consecutive float2 = 256B coalesced).
// ---------------------------------------------------------------------------
__global__ __launch_bounds__(512, 2) void gemm_pointwise(
    const unsigned short* __restrict__ xb, const unsigned short* __restrict__ Wb,
    __half2* __restrict__ cvb, float2* __restrict__ CVagg)
{
    __shared__ char lds[98304];   // 3 bufs x 32KB

    const int th   = threadIdx.x;
    const int lane = th & 63;
    const int wave = th >> 6;      // 0..7
    const int wm = wave >> 2;      // 0..1 -> m offset 0/128
    const int wn = wave & 3;       // 0..3 -> d offset 32*wn

    const int wg  = blockIdx.x;                    // 512 wgs, 8 XCDs
    const int swz = (wg & 7) * 64 + (wg >> 3);     // bijective XCD swizzle
    const int m0 = (swz >> 3) * 256;
    const int d0 = (swz & 7) * 128;

    f32x16 acch[4], accg[4];
#pragma unroll
    for (int i = 0; i < 4; ++i)
#pragma unroll
        for (int r = 0; r < 16; ++r) { acch[i][r] = 0.0f; accg[i][r] = 0.0f; }

    // staging: 512 thr x 16B = 8KB = 128 rows of 64B per stage16 call
    const int srow = th >> 2;                               // 0..127
    const int scol = (((th & 3) ^ ((th >> 3) & 3)) * 8);    // pre-swizzled col
    const unsigned short* srcA  = xb + (size_t)(m0 + srow)       * K_ + scol;
    const unsigned short* srcA2 = xb + (size_t)(m0 + 128 + srow) * K_ + scol;
    const unsigned short* srcBh = Wb + (size_t)(d0 + srow)       * K_ + scol;
    const unsigned short* srcBg = Wb + (size_t)(D_ + d0 + srow)  * K_ + scol;
    char* const wuo = lds + wave * 1024;   // wave-uniform LDS dest base

    const int r31 = lane & 31;
    const int l5  = lane >> 5;
    const int sx  = (r31 >> 1) & 3;                // swizzle XOR for row r31
    const int ko0 = (l5 ^ sx) * 16;                // kh=0 slot byte
    const int ko1 = ko0 ^ 32;                      // kh=1 (bit1 of slot)
    const int abase  = (wm * 128 + r31) * 64;      // A frag base (mt*2048 step)
    const int bbaseh = 16384 + (wn * 32 + r31) * 64;
    const int bbaseg = bbaseh + 8192;              // +128 rows

    bf16x8 Af[4], Bh, Bg;

#define BAR()  asm volatile("s_barrier" ::: "memory")
#define LGK0() asm volatile("s_waitcnt lgkmcnt(0)" ::: "memory")
#define VMW4() asm volatile("s_waitcnt vmcnt(4)" ::: "memory")
#define VMW0() asm volatile("s_waitcnt vmcnt(0)" ::: "memory")

#define STAGE_A(tt, q) do { const int ko_ = (tt) * 32;                    \
    stage16(srcA  + ko_, (q));                                            \
    stage16(srcA2 + ko_, (q) + 8192); } while (0)
#define STAGE_B(tt, q) do { const int ko_ = (tt) * 32;                    \
    stage16(srcBh + ko_, (q) + 16384);                                    \
    stage16(srcBg + ko_, (q) + 24576); } while (0)

#define TILEBODY(T, P0, Q2, PRE, WAITOP) do {                             \
    /* phase 0: kh=0 */                                                   \
    _Pragma("unroll")                                                     \
    for (int i_ = 0; i_ < 4; ++i_)                                        \
        Af[i_] = *(const bf16x8*)((P0) + abase + i_ * 2048 + ko0);        \
    Bh = *(const bf16x8*)((P0) + bbaseh + ko0);                           \
    Bg = *(const bf16x8*)((P0) + bbaseg + ko0);                           \
    if (PRE) { STAGE_A((T) + 2, (Q2)); }                                  \
    BAR(); LGK0();                                                        \
    __builtin_amdgcn_s_setprio(1);                                        \
    _Pragma("unroll")                                                     \
    for (int i_ = 0; i_ < 4; ++i_) {                                      \
        acch[i_] = __builtin_amdgcn_mfma_f32_32x32x16_bf16(               \
            Af[i_], Bh, acch[i_], 0, 0, 0);                               \
        accg[i_] = __builtin_amdgcn_mfma_f32_32x32x16_bf16(               \
            Af[i_], Bg, accg[i_], 0, 0, 0);                               \
    }                                                                     \
    __builtin_amdgcn_s_setprio(0);                                        \
    BAR();                                                                \
    /* phase 1: kh=1 */                                                   \
    _Pragma("unroll")                                                     \
    for (int i_ = 0; i_ < 4; ++i_)                                        \
        Af[i_] = *(const bf16x8*)((P0) + abase + i_ * 2048 + ko1);        \
    Bh = *(const bf16x8*)((P0) + bbaseh + ko1);                           \
    Bg = *(const bf16x8*)((P0) + bbaseg + ko1);                           \
    if (PRE) { STAGE_B((T) + 2, (Q2)); }                                  \
    BAR(); LGK0();                                                        \
    __builtin_amdgcn_s_setprio(1);                                        \
    _Pragma("unroll")                                                     \
    for (int i_ = 0; i_ < 4; ++i_) {                                      \
        acch[i_] = __builtin_amdgcn_mfma_f32_32x32x16_bf16(               \
            Af[i_], Bh, acch[i_], 0, 0, 0);                               \
        accg[i_] = __builtin_amdgcn_mfma_f32_32x32x16_bf16(               \
            Af[i_], Bg, accg[i_], 0, 0, 0);                               \
    }                                                                     \
    __builtin_amdgcn_s_setprio(0);                                        \
    WAITOP;                                                               \
    BAR();                                                                \
  } while (0)

    // rotating buffer pointers (named, never runtime-indexed — rule #20)
    const char* p0 = lds;
    const char* p1 = lds + 32768;
    const char* p2 = lds + 65536;
    char* q0 = wuo;
    char* q1 = wuo + 32768;
    char* q2 = wuo + 65536;

    // prologue: stage tiles 0,1 (8 calls), wait tile 0 only (counted)
    STAGE_A(0, q0); STAGE_B(0, q0);
    STAGE_A(1, q1); STAGE_B(1, q1);
    VMW4();
    BAR();

#pragma unroll 1
    for (int t = 0; t < NKT - 2; ++t) {   // t = 0..29, stage t+2
        TILEBODY(t, p0, q2, 1, VMW4());
        const char* tp = p0; p0 = p1; p1 = p2; p2 = tp;
        char* tq = q0; q0 = q1; q1 = q2; q2 = tq;
    }
    TILEBODY(NKT - 2, p0, q2, 0, VMW0()); // t=30 (tile 31's loads are old)
    { const char* tp = p0; p0 = p1; p1 = p2; p2 = tp; }
    TILEBODY(NKT - 1, p0, q2, 0, (void)0);  // t=31

#undef TILEBODY
#undef STAGE_A
#undef STAGE_B
#undef BAR
#undef LGK0
#undef VMW4
#undef VMW0

    // ---- epilogue: pointwise + cvb store + fused chunk-(C,V) reduction ----
    // 32x32 C/D: col = lane&31 (d), row = (reg&3)+8*(reg>>2)+4*l5 (m).
    // One chunk (32 rows) = one mt tile. Per-lane groups q: rows 8q+4*l5..+3
    // (ascending reg&3); pair-compose with lane^32; fold q ascending.
    const int d = d0 + wn * 32 + r31;
#pragma unroll
    for (int mt = 0; mt < 4; ++mt) {
        float C4[4], V4[4];
#pragma unroll
        for (int q = 0; q < 4; ++q) { C4[q] = 1.0f; V4[q] = 0.0f; }
#pragma unroll
        for (int reg = 0; reg < 16; ++reg) {
            const int q = reg >> 2;
            const int m = m0 + wm * 128 + mt * 32 + (reg & 3) + 8 * q + 4 * l5;
            float h = acch[mt][reg];
            float g = accg[mt][reg];
            float eg  = __expf(g);
            float c   = fast_rcp(1.0f + eg);  // sigma(-g)
            float z   = eg * c;               // sigma(g)
            float enh = __expf(-h);
            float sh  = fast_rcp(1.0f + enh); // sigma(h)
            float gh  = (h >= 0.0f) ? (h + 0.5f) : sh;
            float v   = z * gh;
            cvb[(size_t)m * D_ + d] = __floats2half2_rn(c, v);
            V4[q] = fmaf(c, V4[q], v);        // compose ascending row
            C4[q] *= c;
        }
        float Cc = 1.0f, Vv = 0.0f;
#pragma unroll
        for (int q = 0; q < 4; ++q) {
            float Cp = __shfl_xor(C4[q], 32);
            float Vp = __shfl_xor(V4[q], 32);
            float Clo = l5 ? Cp : C4[q];
            float Vlo = l5 ? Vp : V4[q];
            float Chi = l5 ? C4[q] : Cp;
            float Vhi = l5 ? V4[q] : Vp;
            float C8 = Chi * Clo;             // rows 8q..8q+7 composed
            float V8 = fmaf(Chi, Vlo, Vhi);
            Vv = fmaf(C8, Vv, V8);            // fold ascending q
            Cc = C8 * Cc;
        }
        if (l5 == 0) {
            const int chunkg = (m0 + wm * 128 + mt * 32) >> 5;
            float2 st; st.x = Cc; st.y = Vv;
            CVagg[(size_t)chunkg * D_ + d] = st;
        }
    }
}

// ---------------------------------------------------------------------------
// Kernel 3: scan across chunks (128 FMA steps, tiny). P[c] = h at chunk entry.
// ---------------------------------------------------------------------------
__global__ __launch_bounds__(256) void chunk_scan(
    const float2* __restrict__ CVagg, float* __restrict__ P)
{
    const int d = blockIdx.x * 256 + threadIdx.x;
    const int b = blockIdx.z;
    float h = 0.0f;
    for (int c = 0; c < NC_; ++c) {
        size_t o = ((size_t)b * NC_ + c) * D_ + d;
        P[o] = h;
        float2 cv = CVagg[o];
        h = fmaf(cv.x, h, cv.y);
    }
}

// ---------------------------------------------------------------------------
// Kernel 4: apply — h = fma(c, h, v) from chunk-entry prefix; write fp32 out.
// ---------------------------------------------------------------------------
__global__ __launch_bounds__(256) void chunk_apply(
    const unsigned int* __restrict__ cvw, const float* __restrict__ P,
    float* __restrict__ out)
{
    const int d = (blockIdx.x * 256 + threadIdx.x) * 2;
    const int c = blockIdx.y;
    const int b = blockIdx.z;
    size_t base = ((size_t)(b * S_ + c * L_)) * D_ + d;
    float2 h2 = *(const float2*)(P + ((size_t)b * NC_ + c) * D_ + d);
    float h0 = h2.x, h1 = h2.y;
    for (int s = 0; s < L_; ++s) {
        uint2 u = *(const uint2*)(cvw + base + (size_t)s * D_);
        float2 p0 = __half22float2(*(const __half2*)&u.x);
        float2 p1 = __half22float2(*(const __half2*)&u.y);
        h0 = fmaf(p0.x, h0, p0.y);
        h1 = fmaf(p1.x, h1, p1.y);
        float2 o2 = {h0, h1};
        *(float2*)(out + base + (size_t)s * D_) = o2;
    }
}

extern "C" void kernel_launch(void* const* d_in, const int* in_sizes, int n_in,
                              void* d_out, int out_size, void* d_ws, size_t ws_size,
                              hipStream_t stream) {
    const float* x = (const float*)d_in[0];   // [B,S,D] fp32
    const float* W = (const float*)d_in[1];   // [2D,D] fp32
    float* out = (float*)d_out;               // [B,S,D] fp32

    float2* CVagg = (float2*)d_ws;                             // B*NC*D float2
    float*  P     = (float*)(CVagg + (size_t)B_ * NC_ * D_);
    __half2* cvb  = (__half2*)(P + (size_t)B_ * NC_ * D_);     // M*D half2
    unsigned short* xb = (unsigned short*)(cvb + (size_t)M_ * D_);  // M*K bf16
    unsigned short* Wb = xb + (size_t)M_ * K_;                      // 2D*K bf16

    const int n8x = M_ * K_ / 8;          // 2,097,152
    const int n8w = 2 * D_ * K_ / 8;      // 262,144
    to_bf16_both<<<(n8x + n8w + 255) / 256, 256, 0, stream>>>(x, W, xb, Wb, n8x, n8w);

    // 512 wgs: 64 m-tiles x 8 d-tiles, XCD-swizzled in-kernel
    gemm_pointwise<<<512, 512, 0, stream>>>(xb, Wb, cvb, CVagg);

    dim3 g3(D_ / 256, 1, B_);      // 4 x 1 x 4
    chunk_scan<<<g3, 256, 0, stream>>>(CVagg, P);

    dim3 g2(D_ / 512, NC_, B_);    // 2 x 128 x 4
    chunk_apply<<<g2, 256, 0, stream>>>((const unsigned int*)cvb, P, out);
}

// Round 12
// 123.833 us; speedup vs baseline: 1.0771x; 1.0771x over previous
//
#include <hip/hip_runtime.h>
#include <hip/hip_bf16.h>
#include <hip/hip_fp16.h>
#include <math.h>
#include <string.h>

#define B_  4
#define S_  4096
#define D_  1024
#define M_  (B_ * S_)   // 16384 rows
#define K_  D_          // 1024 reduction
#define L_  32          // scan chunk length
#define NC_ (S_ / L_)   // 128 chunks per sequence
#define NKT 16          // K_/64 K-tiles (BK=64)

typedef __attribute__((ext_vector_type(8))) short          bf16x8;
typedef __attribute__((ext_vector_type(8))) unsigned short u16x8;
typedef __attribute__((ext_vector_type(4))) float          f32x4;

__device__ __forceinline__ unsigned short f2bf(float f) {
    union { __hip_bfloat16 h; unsigned short u; } cv;
    cv.h = __float2bfloat16(f);
    return cv.u;
}

__device__ __forceinline__ float fast_rcp(float x) {
#if __has_builtin(__builtin_amdgcn_rcpf)
    return __builtin_amdgcn_rcpf(x);
#else
    return 1.0f / x;
#endif
}

__device__ __forceinline__ void stage16(const unsigned short* src, char* dst) {
    __builtin_amdgcn_global_load_lds(
        (const __attribute__((address_space(1))) unsigned int*)src,
        (__attribute__((address_space(3))) unsigned int*)dst, 16, 0, 0);
}

// ---------------------------------------------------------------------------
// Kernel 0: fp32 -> bf16 pre-convert, x and W in ONE launch
// ---------------------------------------------------------------------------
__global__ __launch_bounds__(256) void to_bf16_both(
    const float* __restrict__ x, const float* __restrict__ W,
    unsigned short* __restrict__ xb, unsigned short* __restrict__ Wb,
    int n8x, int n8w)
{
    int i = blockIdx.x * 256 + threadIdx.x;
    const float* src;
    unsigned short* dst;
    int j;
    if (i < n8x) { src = x; dst = xb; j = i; }
    else {
        j = i - n8x;
        if (j >= n8w) return;
        src = W; dst = Wb;
    }
    const float4* p = (const float4*)src + (size_t)j * 2;
    float4 a = p[0], b = p[1];
    u16x8 o;
    o[0] = f2bf(a.x); o[1] = f2bf(a.y); o[2] = f2bf(a.z); o[3] = f2bf(a.w);
    o[4] = f2bf(b.x); o[5] = f2bf(b.y); o[6] = f2bf(b.z); o[7] = f2bf(b.w);
    *(u16x8*)(dst + (size_t)j * 8) = o;
}

// ---------------------------------------------------------------------------
// Kernel 1: round-9 champion GEMM (77us, MfmaUtil 37, 0 bank conflicts):
// BM=256, BN=128d x {h,g}, BK=64, 8 waves (2M x 4N), wave tile 128m x 64c,
// 2-deep LDS (2 x 64KB), 8-phase schedule, 16x16x32 MFMA.
// Fused linear-domain pointwise (c = sigma(-g), v = sigma(g)*g(h)) +
// fused per-32-row-chunk (C,V) affine-map reduction -> CVagg.
// Swizzle involution slot^=(row>>1)&3 on BOTH stage-source and read.
// ---------------------------------------------------------------------------
__global__ __launch_bounds__(512, 2) void gemm_pointwise(
    const unsigned short* __restrict__ xb, const unsigned short* __restrict__ Wb,
    __half2* __restrict__ cvb, float2* __restrict__ CVagg)
{
    __shared__ char lds[131072];   // 2 x 64KB

    const int th   = threadIdx.x;
    const int lane = th & 63;
    const int wave = th >> 6;
    const int wm = wave >> 2;      // 0..1 -> m offset 0/128
    const int wn = wave & 3;       // 0..3 -> d offset 32*wn

    const int wg  = blockIdx.x;                    // 512 wgs, 8 XCDs
    const int swz = (wg & 7) * 64 + (wg >> 3);     // bijective XCD swizzle
    const int m0 = (swz >> 3) * 256;
    const int d0 = (swz & 7) * 128;

    f32x4 acc[8][4];
#pragma unroll
    for (int i = 0; i < 8; ++i)
#pragma unroll
        for (int j = 0; j < 4; ++j)
            acc[i][j] = (f32x4){0.f, 0.f, 0.f, 0.f};

    // staging: 512 thr x 16B = 8KB = 128 rows per round; 8 rounds per K-tile
    const int srow = th >> 2;                               // 0..127
    const int scol = (((th & 3) ^ ((th >> 3) & 3)) * 8);    // pre-swizzled col
    const unsigned short* srcA  = xb + (size_t)(m0 + srow)       * K_ + scol;
    const unsigned short* srcA2 = xb + (size_t)(m0 + 128 + srow) * K_ + scol;
    const unsigned short* srcBh = Wb + (size_t)(d0 + srow)       * K_ + scol;
    const unsigned short* srcBg = Wb + (size_t)(D_ + d0 + srow)  * K_ + scol;
    char* const wuo = lds + wave * 1024;   // wave-uniform LDS dest base

    const int lr = lane & 15;
    const int lq = lane >> 4;
    const int lkb = ((lq ^ ((lr >> 1) & 3)) * 16);            // swizzled slot
    const int aoffb = (wm * 128 + lr) * 64 + lkb;             // A frag base
    const int boffb = 32768 + (wn * 32 + lr) * 64 + lkb;      // B frag base

    bf16x8 Aa[4], Ab[4], Ba[4], Bb[4];

#define BAR()  asm volatile("s_barrier" ::: "memory")
#define LGK0() asm volatile("s_waitcnt lgkmcnt(0)" ::: "memory")
#define VM0()  asm volatile("s_waitcnt vmcnt(0)" ::: "memory")

#define CLUSTER(base, AF, BF) do {                                        \
    __builtin_amdgcn_s_setprio(1);                                        \
    _Pragma("unroll")                                                     \
    for (int i_ = 0; i_ < 4; ++i_)                                        \
        _Pragma("unroll")                                                 \
        for (int j_ = 0; j_ < 4; ++j_)                                    \
            acc[(base) + i_][j_] = __builtin_amdgcn_mfma_f32_16x16x32_bf16(\
                AF[i_], BF[j_], acc[(base) + i_][j_], 0, 0, 0);           \
    __builtin_amdgcn_s_setprio(0);                                        \
  } while (0)

    // prologue: stage tile 0 into buf0, drain, read phase-0 frags
    stage16(srcA,       wuo + 0);
    stage16(srcA2,      wuo + 8192);
    stage16(srcA  + 32, wuo + 16384);
    stage16(srcA2 + 32, wuo + 24576);
    stage16(srcBh,      wuo + 32768);
    stage16(srcBg,      wuo + 40960);
    stage16(srcBh + 32, wuo + 49152);
    stage16(srcBg + 32, wuo + 57344);
    VM0();
    BAR();
    {
        const char* bc = lds;
#pragma unroll
        for (int i = 0; i < 4; ++i)
            Aa[i] = *(const bf16x8*)(bc + aoffb + i * 1024);
#pragma unroll
        for (int j = 0; j < 2; ++j) {
            Ba[j]     = *(const bf16x8*)(bc + boffb + j * 1024);
            Ba[j + 2] = *(const bf16x8*)(bc + boffb + 8192 + j * 1024);
        }
    }

#pragma unroll 1
    for (int t = 0; t < NKT; ++t) {
        const char* bc  = lds + (t & 1) * 65536;        // compute buf (read)
        char*       bn  = wuo + ((t + 1) & 1) * 65536;  // next buf (stage dest)
        const char* bnr = lds + ((t + 1) & 1) * 65536;  // next buf (read)
        const int kof = (t + 1) * 64;
        const bool pre = (t < NKT - 1);

        // ---- phase 0: MFMA acc[0..3] = A(mh0,k0) x B(k0) ----
#pragma unroll
        for (int i = 0; i < 4; ++i)
            Ab[i] = *(const bf16x8*)(bc + aoffb + 4096 + i * 1024);    // (mh1,k0)
        if (pre) {
            stage16(srcA  + kof,      bn + 0);
            stage16(srcA2 + kof,      bn + 8192);
            stage16(srcA  + kof + 32, bn + 16384);
            stage16(srcA2 + kof + 32, bn + 24576);
        }
        BAR(); LGK0();
        CLUSTER(0, Aa, Ba);
        BAR();

        // ---- phase 1: MFMA acc[4..7] = A(mh1,k0) x B(k0) ----
#pragma unroll
        for (int i = 0; i < 4; ++i)
            Aa[i] = *(const bf16x8*)(bc + aoffb + 16384 + i * 1024);   // (mh0,k1)
#pragma unroll
        for (int j = 0; j < 2; ++j) {
            Bb[j]     = *(const bf16x8*)(bc + boffb + 16384 + j * 1024);         // B(k1) h
            Bb[j + 2] = *(const bf16x8*)(bc + boffb + 16384 + 8192 + j * 1024);  // B(k1) g
        }
        if (pre) {
            stage16(srcBh + kof,      bn + 32768);
            stage16(srcBg + kof,      bn + 40960);
            stage16(srcBh + kof + 32, bn + 49152);
            stage16(srcBg + kof + 32, bn + 57344);
        }
        BAR(); LGK0();
        CLUSTER(4, Ab, Ba);
        BAR();

        // ---- phase 2: MFMA acc[0..3] = A(mh0,k1) x B(k1) ----
#pragma unroll
        for (int i = 0; i < 4; ++i)
            Ab[i] = *(const bf16x8*)(bc + aoffb + 4096 + 16384 + i * 1024);  // (mh1,k1)
        BAR(); LGK0();
        CLUSTER(0, Aa, Bb);
        BAR();

        // ---- phase 3: cross-buf sync, prefetch next frags, last cluster ----
        VM0();           // t+1's 8 loads issued >=2 phases ago -> cheap drain
        BAR();           // buf[(t+1)&1] now globally valid
        if (pre) {       // issue next tile's phase-0 frag reads BEFORE MFMAs
#pragma unroll
            for (int i = 0; i < 4; ++i)
                Aa[i] = *(const bf16x8*)(bnr + aoffb + i * 1024);
#pragma unroll
            for (int j = 0; j < 2; ++j) {
                Ba[j]     = *(const bf16x8*)(bnr + boffb + j * 1024);
                Ba[j + 2] = *(const bf16x8*)(bnr + boffb + 8192 + j * 1024);
            }
        }
        CLUSTER(4, Ab, Bb);
        // no trailing barrier: next phase-0 stages into buf[t&1], which no
        // wave reads after phase 2's closing barrier (phase 3 = regs + bnr)
    }
#undef CLUSTER
#undef BAR
#undef LGK0
#undef VM0

    // ---- epilogue: pointwise + cvb store + fused chunk-(C,V) reduction ----
    // C/D: col = lane&15 (d), row = lq*4 + reg (m). Lane rows for frag mi:
    // wm*128 + mi*16 + lq*4 + {0..3}. Chunk (32 rows) = mi pair; compose
    // r-fold -> lq-compose (shfl_xor 16,32) -> mi-pair; write at lq==0.
#pragma unroll
    for (int mp = 0; mp < 4; ++mp) {          // mi pair (2mp, 2mp+1)
        float C16[2][2], V16[2][2];
#pragma unroll
        for (int hf = 0; hf < 2; ++hf) {
            const int mi = mp * 2 + hf;
#pragma unroll
            for (int nj = 0; nj < 2; ++nj) {
                float C4 = 1.0f, V4 = 0.0f;
                const int d = d0 + wn * 32 + nj * 16 + lr;
#pragma unroll
                for (int r = 0; r < 4; ++r) {
                    int m = m0 + wm * 128 + mi * 16 + lq * 4 + r;
                    float h = acc[mi][nj][r];         // hidden
                    float g = acc[mi][nj + 2][r];     // gate, same d
                    float eg  = __expf(g);
                    float c   = fast_rcp(1.0f + eg);  // sigma(-g)
                    float z   = eg * c;               // sigma(g)
                    float enh = __expf(-h);
                    float sh  = fast_rcp(1.0f + enh); // sigma(h)
                    float gh  = (h >= 0.0f) ? (h + 0.5f) : sh;
                    float v   = z * gh;
                    cvb[(size_t)m * D_ + d] = __floats2half2_rn(c, v);
                    V4 = fmaf(c, V4, v);              // compose ascending r
                    C4 *= c;
                }
                // lq-compose (rows base+lq*4, ascending lq):
                float Ca = __shfl_xor(C4, 16), Va = __shfl_xor(V4, 16);
                float Clo = (lq & 1) ? Ca : C4, Vlo = (lq & 1) ? Va : V4;
                float Chi = (lq & 1) ? C4 : Ca, Vhi = (lq & 1) ? V4 : Va;
                float C2 = Clo * Chi, V2 = fmaf(Chi, Vlo, Vhi);
                float Cb = __shfl_xor(C2, 32), Vb = __shfl_xor(V2, 32);
                float Cl2 = (lq & 2) ? Cb : C2, Vl2 = (lq & 2) ? Vb : V2;
                float Ch2 = (lq & 2) ? C2 : Cb, Vh2 = (lq & 2) ? V2 : Vb;
                C16[hf][nj] = Cl2 * Ch2;
                V16[hf][nj] = fmaf(Ch2, Vl2, Vh2);
            }
        }
        if (lq == 0) {
            const int chunkg = (m0 + wm * 128 + mp * 32) >> 5;  // global chunk
#pragma unroll
            for (int nj = 0; nj < 2; ++nj) {
                float C32 = C16[0][nj] * C16[1][nj];
                float V32 = fmaf(C16[1][nj], V16[0][nj], V16[1][nj]);
                const int d = d0 + wn * 32 + nj * 16 + lr;
                float2 st; st.x = C32; st.y = V32;
                CVagg[(size_t)chunkg * D_ + d] = st;
            }
        }
    }
}

// ---------------------------------------------------------------------------
// Kernel 3: scan across chunks (128 FMA steps, tiny). P[c] = h at chunk entry.
// ---------------------------------------------------------------------------
__global__ __launch_bounds__(256) void chunk_scan(
    const float2* __restrict__ CVagg, float* __restrict__ P)
{
    const int d = blockIdx.x * 256 + threadIdx.x;
    const int b = blockIdx.z;
    float h = 0.0f;
    for (int c = 0; c < NC_; ++c) {
        size_t o = ((size_t)b * NC_ + c) * D_ + d;
        P[o] = h;
        float2 cv = CVagg[o];
        h = fmaf(cv.x, h, cv.y);
    }
}

// ---------------------------------------------------------------------------
// Kernel 4: apply — h = fma(c, h, v) from chunk-entry prefix.
// Nontemporal: cvb is read-once here; out is write-once, never re-read.
// ---------------------------------------------------------------------------
__global__ __launch_bounds__(256) void chunk_apply(
    const unsigned long long* __restrict__ cvw,  // half2-pairs as u64, [m][d/2]
    const float* __restrict__ P, float* __restrict__ out)
{
    const int d = (blockIdx.x * 256 + threadIdx.x) * 2;
    const int c = blockIdx.y;
    const int b = blockIdx.z;
    size_t base2 = (((size_t)(b * S_ + c * L_)) * D_ + d) >> 1;  // u64 units
    float2 h2 = *(const float2*)(P + ((size_t)b * NC_ + c) * D_ + d);
    float h0 = h2.x, h1 = h2.y;
    unsigned long long* outp = (unsigned long long*)out;
    union Cvt { unsigned long long ull; uint2 u2; float2 f2; };
#pragma unroll
    for (int s = 0; s < L_; ++s) {
        Cvt in;
        in.ull = __builtin_nontemporal_load(cvw + base2 + (size_t)s * (D_ / 2));
        float2 p0 = __half22float2(*(const __half2*)&in.u2.x);
        float2 p1 = __half22float2(*(const __half2*)&in.u2.y);
        h0 = fmaf(p0.x, h0, p0.y);
        h1 = fmaf(p1.x, h1, p1.y);
        Cvt o;
        o.f2.x = h0; o.f2.y = h1;
        __builtin_nontemporal_store(o.ull, outp + base2 + (size_t)s * (D_ / 2));
    }
}

extern "C" void kernel_launch(void* const* d_in, const int* in_sizes, int n_in,
                              void* d_out, int out_size, void* d_ws, size_t ws_size,
                              hipStream_t stream) {
    const float* x = (const float*)d_in[0];   // [B,S,D] fp32
    const float* W = (const float*)d_in[1];   // [2D,D] fp32
    float* out = (float*)d_out;               // [B,S,D] fp32

    float2* CVagg = (float2*)d_ws;                             // B*NC*D float2
    float*  P     = (float*)(CVagg + (size_t)B_ * NC_ * D_);
    __half2* cvb  = (__half2*)(P + (size_t)B_ * NC_ * D_);     // M*D half2
    unsigned short* xb = (unsigned short*)(cvb + (size_t)M_ * D_);  // M*K bf16
    unsigned short* Wb = xb + (size_t)M_ * K_;                      // 2D*K bf16

    const int n8x = M_ * K_ / 8;          // 2,097,152
    const int n8w = 2 * D_ * K_ / 8;      // 262,144
    to_bf16_both<<<(n8x + n8w + 255) / 256, 256, 0, stream>>>(x, W, xb, Wb, n8x, n8w);

    // 512 wgs: 64 m-tiles x 8 d-tiles, XCD-swizzled in-kernel
    gemm_pointwise<<<512, 512, 0, stream>>>(xb, Wb, cvb, CVagg);

    dim3 g3(D_ / 256, 1, B_);      // 4 x 1 x 4
    chunk_scan<<<g3, 256, 0, stream>>>(CVagg, P);

    dim3 g2(D_ / 512, NC_, B_);    // 2 x 128 x 4
    chunk_apply<<<g2, 256, 0, stream>>>((const unsigned long long*)cvb, P, out);
}